// Round 9
// baseline (245.692 us; speedup 1.0000x reference)
//
#include <hip/hip_runtime.h>
#include <stdint.h>

// ---------------------------------------------------------------------------
// 2-layer GCN. g = (xW) row-scaled by dinv, stored BF16 (MFMA bf16 GEMM).
// out[d] = dinv[d] * (sum_{s in N(d)} g[s] + g[d]) + b, f32 accumulate.
// R9: packed 4B edge records (dstLocal<<16|src), prep folded into scatter,
// bucket scan folded (redundantly) into bucket_build. 7 dispatches total.
// agg at measured ~3.9 TB/s random-gather plateau; gemm at memory floor.
// ---------------------------------------------------------------------------

typedef unsigned short u16;
typedef __bf16 bf16x8 __attribute__((ext_vector_type(8)));
typedef float f32x4 __attribute__((ext_vector_type(4)));
typedef unsigned short us8 __attribute__((ext_vector_type(8)));
typedef unsigned short us4 __attribute__((ext_vector_type(4)));

#define BSHIFT 8                  // bucket = dst >> 8 (256 nodes/bucket)
#define BSTRIDE 6144              // record slots per bucket (mean 5102, +14 sigma)
#define EPT 8                     // edges per thread in scatter
#define TILE (256 * EPT)

__device__ __forceinline__ float bf2f(u16 u) {
    union { unsigned i; float f; } c;
    c.i = ((unsigned)u) << 16;
    return c.f;
}
__device__ __forceinline__ u16 f2bf(float f) {
    union { float f; unsigned i; } c;
    c.f = f;
    unsigned i = c.i;
    return (u16)((i + 0x7FFF + ((i >> 16) & 1)) >> 16);   // RNE
}

// ---------------------------------------------------------------------------
// CSR build, pass 1: tile-sorted scatter of packed (dstLocal<<16|src) records
// into bucket segments (write-local). Blocks 0..255 also convert W->Wt bf16.
// ---------------------------------------------------------------------------
__global__ __launch_bounds__(256) void scatter_kernel(const int* __restrict__ src,
        const int* __restrict__ dst, int* __restrict__ bcursor,
        unsigned* __restrict__ rec, int E,
        const float* __restrict__ W1, const float* __restrict__ W2,
        u16* __restrict__ Wt1, u16* __restrict__ Wt2) {
    __shared__ int cnt[256], lcur[256], gbase[256];
    const int t = threadIdx.x;
    if (blockIdx.x < 256) {               // folded weight transpose/convert
        int wt = blockIdx.x * 256 + t;    // 0..65535
        int k = wt >> 8, nn = wt & 255;
        size_t idx = ((size_t)nn << 8) + k;
        Wt1[idx] = f2bf(W1[wt]);
        Wt2[idx] = f2bf(W2[wt]);
    }
    const int base = blockIdx.x * TILE;
    cnt[t] = 0;
    __syncthreads();
    int d[EPT], s[EPT], b[EPT];
#pragma unroll
    for (int k = 0; k < EPT; k++) {
        int e = base + t + k * 256;
        if (e < E) {
            d[k] = dst[e];
            s[k] = src[e];
            b[k] = d[k] >> BSHIFT;
            atomicAdd(&cnt[b[k]], 1);
        } else b[k] = -1;
    }
    __syncthreads();
    int c = cnt[t];
    if (c > 0) gbase[t] = atomicAdd(&bcursor[t], c);
    lcur[t] = 0;
    __syncthreads();
#pragma unroll
    for (int k = 0; k < EPT; k++) {
        if (b[k] >= 0) {
            int r = atomicAdd(&lcur[b[k]], 1);
            rec[(size_t)b[k] * BSTRIDE + gbase[b[k]] + r] =
                ((unsigned)(d[k] & 255) << 16) | (unsigned)s[k];
        }
    }
}

// ---------------------------------------------------------------------------
// CSR build, pass 2 (scan folded in): every block redundantly scans the
// bucket counts in LDS, then does per-bucket local count + scan + scatter
// into csr_src; emits row_ptr and dinv.
// ---------------------------------------------------------------------------
__global__ __launch_bounds__(256) void bucket_build(const unsigned* __restrict__ rec,
        const int* __restrict__ bcursor, int* __restrict__ row_ptr,
        float* __restrict__ dinv, int* __restrict__ csr_src,
        int n, int NB, int E) {
    __shared__ int cnt[256], loff[256], sc[256];
    const int b = blockIdx.x;
    const int t = threadIdx.x;
    // redundant exclusive scan of bucket counts -> this bucket's base
    int bv = (t < NB) ? bcursor[t] : 0;
    sc[t] = bv;
    __syncthreads();
    for (int off = 1; off < 256; off <<= 1) {
        int u = (t >= off) ? sc[t - off] : 0;
        __syncthreads();
        sc[t] += u;
        __syncthreads();
    }
    __shared__ int base_s, m_s;
    if (t == b) { base_s = sc[t] - bv; m_s = bv; }
    if (b == 0 && t == 0) row_ptr[n] = E;
    __syncthreads();
    const int m = m_s;
    const int base = base_s;
    const unsigned* r = rec + (size_t)b * BSTRIDE;
    cnt[t] = 0;
    __syncthreads();
    for (int i = t; i < m; i += 256)
        atomicAdd(&cnt[r[i] >> 16], 1);
    __syncthreads();
    int c = cnt[t];
    sc[t] = c;
    __syncthreads();
    for (int off = 1; off < 256; off <<= 1) {
        int u = (t >= off) ? sc[t - off] : 0;
        __syncthreads();
        sc[t] += u;
        __syncthreads();
    }
    loff[t] = sc[t] - c;
    int node = (b << BSHIFT) + t;
    if (node < n) {
        row_ptr[node] = base + loff[t];
        dinv[node] = 1.0f / sqrtf((float)c + 1.0f);
    }
    __syncthreads();
    sc[t] = loff[t];                      // live cursors
    __syncthreads();
    for (int i = t; i < m; i += 256) {
        unsigned e = r[i];
        int idx = atomicAdd(&sc[e >> 16], 1);
        csr_src[base + idx] = (int)(e & 0xFFFFu);
    }
}

// ---------------------------------------------------------------------------
// MFMA GEMM: g[M x 256] = bf16( dinv[row] * (A[M x 256] @ W) )
// A f32 (layer1, converted in staging) or bf16 (layer2). W given as Wt[n][k].
// 128x128 tile, 4 waves 2x2, K=256, per-K-tile staging of A and B
// (20 KB LDS -> 4 blocks/CU).
// mfma_f32_16x16x32_bf16 layouts: A(row=l&15, k=(l>>4)*8+j),
// B(col=l&15, k=(l>>4)*8+j), D(col=l&15, row=(l>>4)*4+r).
// ---------------------------------------------------------------------------
template<bool AF32>
__global__ __launch_bounds__(256, 4) void mfma_gemm(const void* __restrict__ Ap,
        const u16* __restrict__ Wt, const float* __restrict__ dinv,
        u16* __restrict__ g, int M) {
    __shared__ u16 As[128][40];     // [row][k] 10240 B
    __shared__ u16 Bs[128][40];     // [col][k] 10240 B
    const int tid = threadIdx.x;
    const int row0 = blockIdx.x * 128;
    const int col0 = blockIdx.y * 128;

    const int lane = tid & 63;
    const int w = tid >> 6;
    const int wr = w >> 1, wc = w & 1;
    const int l15 = lane & 15, kg = lane >> 4;

    f32x4 acc[4][4];
#pragma unroll
    for (int mi = 0; mi < 4; mi++)
#pragma unroll
        for (int ni = 0; ni < 4; ni++)
            acc[mi][ni] = (f32x4){0.f, 0.f, 0.f, 0.f};

    const int srow = tid >> 1;          // 0..127 (A row / B col)
    const int shalf = tid & 1;          // which 16-element k-half
    const int grow = row0 + srow;

    for (int k0 = 0; k0 < 256; k0 += 32) {
        // stage A rows [row0,row0+128) x k-tile
        if (AF32) {
            const float* srcp = (const float*)Ap + ((size_t)grow << 8) + k0 + shalf * 16;
            float4 v[4];
#pragma unroll
            for (int q = 0; q < 4; q++)
                v[q] = (grow < M) ? *(const float4*)(srcp + q * 4)
                                  : make_float4(0.f, 0.f, 0.f, 0.f);
            u16 tmp[16];
#pragma unroll
            for (int q = 0; q < 4; q++) {
                tmp[q * 4 + 0] = f2bf(v[q].x); tmp[q * 4 + 1] = f2bf(v[q].y);
                tmp[q * 4 + 2] = f2bf(v[q].z); tmp[q * 4 + 3] = f2bf(v[q].w);
            }
            *(us8*)&As[srow][shalf * 16]     = *(us8*)&tmp[0];
            *(us8*)&As[srow][shalf * 16 + 8] = *(us8*)&tmp[8];
        } else {
            const u16* srcp = (const u16*)Ap + ((size_t)grow << 8) + k0 + shalf * 16;
            us8 z = {0, 0, 0, 0, 0, 0, 0, 0};
            us8 a0 = (grow < M) ? *(const us8*)srcp       : z;
            us8 a1 = (grow < M) ? *(const us8*)(srcp + 8) : z;
            *(us8*)&As[srow][shalf * 16]     = a0;
            *(us8*)&As[srow][shalf * 16 + 8] = a1;
        }
        // stage B cols [col0,col0+128) x k-tile (Wt is [n][k] bf16)
        {
            const u16* srcp = Wt + (((size_t)(col0 + srow)) << 8) + k0 + shalf * 16;
            *(us8*)&Bs[srow][shalf * 16]     = *(const us8*)srcp;
            *(us8*)&Bs[srow][shalf * 16 + 8] = *(const us8*)(srcp + 8);
        }
        __syncthreads();
        bf16x8 af[4], bfv[4];
#pragma unroll
        for (int mi = 0; mi < 4; mi++)
            af[mi] = *(const bf16x8*)&As[wr * 64 + mi * 16 + l15][kg * 8];
#pragma unroll
        for (int ni = 0; ni < 4; ni++)
            bfv[ni] = *(const bf16x8*)&Bs[wc * 64 + ni * 16 + l15][kg * 8];
#pragma unroll
        for (int mi = 0; mi < 4; mi++)
#pragma unroll
            for (int ni = 0; ni < 4; ni++)
                acc[mi][ni] = __builtin_amdgcn_mfma_f32_16x16x32_bf16(
                    af[mi], bfv[ni], acc[mi][ni], 0, 0, 0);
        __syncthreads();
    }

#pragma unroll
    for (int mi = 0; mi < 4; mi++) {
#pragma unroll
        for (int r = 0; r < 4; r++) {
            int gr = row0 + wr * 64 + mi * 16 + kg * 4 + r;
            if (gr < M) {
                float s = dinv[gr];
                u16* dstp = g + ((size_t)gr << 8) + col0 + wc * 64 + l15;
#pragma unroll
                for (int ni = 0; ni < 4; ni++)
                    dstp[ni * 16] = f2bf(acc[mi][ni][r] * s);
            }
        }
    }
}

// ---------------------------------------------------------------------------
// Aggregation: one wave per node, lane = 4 cols (ushort4 bf16 gather,
// 8B/lane = 512B/edge/wave). f32 accumulate, x8 unroll. Epilogue scales by
// dinv, adds bias, optional relu; f32 or bf16 output.
// ---------------------------------------------------------------------------
template<bool OUT16>
__global__ __launch_bounds__(256) void agg_kernel(const u16* __restrict__ g,
        const int* __restrict__ csr_src, const int* __restrict__ row_ptr,
        const float* __restrict__ dinv, const float* __restrict__ bias,
        void* __restrict__ outp, int n, int do_relu) {
    int wid = threadIdx.x >> 6;
    int lane = threadIdx.x & 63;
    int node = blockIdx.x * 4 + wid;
    if (node >= n) return;
    int jb = row_ptr[node], je = row_ptr[node + 1];
    const size_t co = (size_t)(lane * 4);
    float4 a0 = make_float4(0.f, 0.f, 0.f, 0.f);
    float4 a1 = make_float4(0.f, 0.f, 0.f, 0.f);
    int j = jb;
    for (; j + 8 <= je; j += 8) {
        int s0 = csr_src[j + 0], s1 = csr_src[j + 1];
        int s2 = csr_src[j + 2], s3 = csr_src[j + 3];
        int s4 = csr_src[j + 4], s5 = csr_src[j + 5];
        int s6 = csr_src[j + 6], s7 = csr_src[j + 7];
        ushort4 v0 = *(const ushort4*)(g + ((size_t)s0 << 8) + co);
        ushort4 v1 = *(const ushort4*)(g + ((size_t)s1 << 8) + co);
        ushort4 v2 = *(const ushort4*)(g + ((size_t)s2 << 8) + co);
        ushort4 v3 = *(const ushort4*)(g + ((size_t)s3 << 8) + co);
        ushort4 v4 = *(const ushort4*)(g + ((size_t)s4 << 8) + co);
        ushort4 v5 = *(const ushort4*)(g + ((size_t)s5 << 8) + co);
        ushort4 v6 = *(const ushort4*)(g + ((size_t)s6 << 8) + co);
        ushort4 v7 = *(const ushort4*)(g + ((size_t)s7 << 8) + co);
        a0.x += bf2f(v0.x); a0.y += bf2f(v0.y); a0.z += bf2f(v0.z); a0.w += bf2f(v0.w);
        a1.x += bf2f(v1.x); a1.y += bf2f(v1.y); a1.z += bf2f(v1.z); a1.w += bf2f(v1.w);
        a0.x += bf2f(v2.x); a0.y += bf2f(v2.y); a0.z += bf2f(v2.z); a0.w += bf2f(v2.w);
        a1.x += bf2f(v3.x); a1.y += bf2f(v3.y); a1.z += bf2f(v3.z); a1.w += bf2f(v3.w);
        a0.x += bf2f(v4.x); a0.y += bf2f(v4.y); a0.z += bf2f(v4.z); a0.w += bf2f(v4.w);
        a1.x += bf2f(v5.x); a1.y += bf2f(v5.y); a1.z += bf2f(v5.z); a1.w += bf2f(v5.w);
        a0.x += bf2f(v6.x); a0.y += bf2f(v6.y); a0.z += bf2f(v6.z); a0.w += bf2f(v6.w);
        a1.x += bf2f(v7.x); a1.y += bf2f(v7.y); a1.z += bf2f(v7.z); a1.w += bf2f(v7.w);
    }
    for (; j < je; ++j) {
        int s = csr_src[j];
        ushort4 v = *(const ushort4*)(g + ((size_t)s << 8) + co);
        a0.x += bf2f(v.x); a0.y += bf2f(v.y); a0.z += bf2f(v.z); a0.w += bf2f(v.w);
    }
    ushort4 gd = *(const ushort4*)(g + ((size_t)node << 8) + co);
    float dn = dinv[node];
    float4 bv = *(const float4*)(bias + co);
    float4 o;
    o.x = (a0.x + a1.x + bf2f(gd.x)) * dn + bv.x;
    o.y = (a0.y + a1.y + bf2f(gd.y)) * dn + bv.y;
    o.z = (a0.z + a1.z + bf2f(gd.z)) * dn + bv.z;
    o.w = (a0.w + a1.w + bf2f(gd.w)) * dn + bv.w;
    if (do_relu) {
        o.x = fmaxf(o.x, 0.f); o.y = fmaxf(o.y, 0.f);
        o.z = fmaxf(o.z, 0.f); o.w = fmaxf(o.w, 0.f);
    }
    if (OUT16) {
        us4 ov = { f2bf(o.x), f2bf(o.y), f2bf(o.z), f2bf(o.w) };
        *(us4*)((u16*)outp + ((size_t)node << 8) + co) = ov;
    } else {
        *(float4*)((float*)outp + ((size_t)node << 8) + co) = o;
    }
}

extern "C" void kernel_launch(void* const* d_in, const int* in_sizes, int n_in,
                              void* d_out, int out_size, void* d_ws, size_t ws_size,
                              hipStream_t stream) {
    // inputs: 0 gene_ind_vec (unused), 1 edge_index, 2 embedding, 3 W1, 4 b1, 5 W2, 6 b2
    const int*   edge_index = (const int*)d_in[1];
    const float* embedding  = (const float*)d_in[2];
    const float* W1 = (const float*)d_in[3];
    const float* b1 = (const float*)d_in[4];
    const float* W2 = (const float*)d_in[5];
    const float* b2 = (const float*)d_in[6];

    const int E = in_sizes[1] / 2;
    const int n = in_sizes[2] / 256;
    const int* src = edge_index;
    const int* dst = edge_index + E;
    const int NB = (n + 255) >> BSHIFT;     // buckets (196)

    char* ws = (char*)d_ws;
    int* row_ptr = (int*)ws;    ws += ((size_t)n + 1) * 4;
    float* dinv = (float*)ws;   ws += (size_t)n * 4;
    int* bcursor = (int*)ws;    ws += 256 * 4;
    int* csr_src = (int*)ws;    ws += (size_t)E * 4;
    u16* Wt1 = (u16*)ws;        ws += 65536 * 2;
    u16* Wt2 = (u16*)ws;        ws += 65536 * 2;
    ws = (char*)(((uintptr_t)ws + 127) & ~(uintptr_t)127);
    unsigned* rec = (unsigned*)ws; ws += (size_t)NB * BSTRIDE * 4;
    ws = (char*)(((uintptr_t)ws + 127) & ~(uintptr_t)127);
    u16* g = (u16*)ws;          // n*256 bf16 (25.6 MB)
    u16* x1 = (u16*)d_out;      // bf16 x1 scratch in d_out; consumed by gemm2
                                // before final agg overwrites d_out

    hipMemsetAsync(bcursor, 0, 256 * 4, stream);
    scatter_kernel<<<(E + TILE - 1) / TILE, 256, 0, stream>>>(src, dst, bcursor, rec, E,
                                                              W1, W2, Wt1, Wt2);
    bucket_build<<<NB, 256, 0, stream>>>(rec, bcursor, row_ptr, dinv, csr_src, n, NB, E);

    dim3 gg((n + 127) / 128, 2);
    // layer 1: g1 = bf16(dinv*(X@W1)); x1 = bf16(relu(dinv*(agg+self)+b1))
    mfma_gemm<true><<<gg, 256, 0, stream>>>(embedding, Wt1, dinv, g, n);
    agg_kernel<true><<<(n + 3) / 4, 256, 0, stream>>>(g, csr_src, row_ptr, dinv, b1, x1, n, 1);
    // layer 2: g2 = bf16(dinv*(x1@W2)); out = dinv*(agg+self)+b2 (f32)
    mfma_gemm<false><<<gg, 256, 0, stream>>>(x1, Wt2, dinv, g, n);
    agg_kernel<false><<<(n + 3) / 4, 256, 0, stream>>>(g, csr_src, row_ptr, dinv, b2, (float*)d_out, n, 0);
}